// Round 9
// baseline (457.157 us; speedup 1.0000x reference)
//
#include <hip/hip_runtime.h>
#include <hip/hip_bf16.h>

#define DIM    768
#define HEADS  12
#define DHEAD  64
#define BATCH  4
#define SEQ    2048
#define NROW   (BATCH * SEQ)   // 8192
#define QKVN   (3 * DIM)       // 2304
#define FACTOR 0.125f          // 64^-0.5
#define QSCALE 0.18033688011112042f  // FACTOR * log2(e), folded into Wqt rows <768

typedef __attribute__((ext_vector_type(8))) short short8;    // 8 bf16 = 4 VGPR
typedef __attribute__((ext_vector_type(4))) float floatx4;   // 16x16 C/D
typedef __attribute__((ext_vector_type(16))) float floatx16; // 32x32 C/D
typedef __attribute__((ext_vector_type(4))) unsigned uintx4;

__device__ __forceinline__ floatx4 mfma16(short8 a, short8 b, floatx4 c) {
    return __builtin_amdgcn_mfma_f32_16x16x32_bf16(a, b, c, 0, 0, 0);
}
__device__ __forceinline__ floatx16 mfma32(short8 a, short8 b, floatx16 c) {
    return __builtin_amdgcn_mfma_f32_32x32x16_bf16(a, b, c, 0, 0, 0);
}

// async global->LDS, 16B per lane; lds base must be wave-uniform,
// deposits at base + lane*16 (lane-ordered source REQUIRED for coalescing)
__device__ __forceinline__ void glds16(const void* g, void* l) {
    __builtin_amdgcn_global_load_lds((const __attribute__((address_space(1))) void*)g,
                                     (__attribute__((address_space(3))) void*)l,
                                     16, 0, 0);
}

// branchless RNE fp32->bf16 (finite values only)
__device__ __forceinline__ short rne16(float f) {
    unsigned u = __builtin_bit_cast(unsigned, f);
    return (short)((u + 0x7fffu + ((u >> 16) & 1u)) >> 16);
}
__device__ __forceinline__ unsigned pack2(float lo, float hi) {
    unsigned ul = __builtin_bit_cast(unsigned, lo);
    unsigned uh = __builtin_bit_cast(unsigned, hi);
    ul = (ul + 0x7fffu + ((ul >> 16) & 1u)) >> 16;
    uh = (uh + 0x7fffu + ((uh >> 16) & 1u)) & 0xffff0000u;
    return ul | uh;
}
// HW packed RNE cvt (gfx950): lo -> bits[15:0], hi -> bits[31:16]
__device__ __forceinline__ unsigned cvtpk(float lo, float hi) {
    unsigned r;
    asm("v_cvt_pk_bf16_f32 %0, %1, %2" : "=v"(r) : "v"(lo), "v"(hi));
    return r;
}

// XOR-swizzled tile addressing, 64 bf16 per row (GEMM staging paths)
__device__ __forceinline__ int swz8(int row, int col) {
    return (row << 6) + ((((col >> 3) ^ row) & 7) << 3) + (col & 7);
}

// ---------------------------------------------------------------------------
// prep (fused): blocks [0,6144)   : x fp32 -> bf16
//               blocks [6144,7872): Wqkv transpose+permute (+QSCALE rows<768)
//               blocks [7872,8448): Wout transpose
// ---------------------------------------------------------------------------
__global__ __launch_bounds__(256) void prep(const float* __restrict__ x,
                                            short* __restrict__ xb,
                                            const float* __restrict__ Wqkv,
                                            short* __restrict__ Wqt,
                                            const float* __restrict__ Wout,
                                            short* __restrict__ Wot) {
    __shared__ short T[32][33];
    int blk = blockIdx.x;
    if (blk < 6144) {
        int g = blk * 256 + threadIdx.x;
        float4 v = ((const float4*)x)[g];
        uint2 o;
        o.x = pack2(v.x, v.y);
        o.y = pack2(v.z, v.w);
        ((uint2*)xb)[g] = o;
        return;
    }
    blk -= 6144;
    const float* W;
    short* Wt;
    int N, permute, bx, by;
    if (blk < 1728) { W = Wqkv; Wt = Wqt; N = QKVN; permute = 1; bx = blk % 72; by = blk / 72; }
    else { blk -= 1728; W = Wout; Wt = Wot; N = DIM; permute = 0; bx = blk % 24; by = blk / 24; }

    int n0 = bx * 32, k0 = by * 32;
    int c = threadIdx.x & 31, r0 = threadIdx.x >> 5;
    for (int r = r0; r < 32; r += 8)
        T[r][c] = rne16(W[(size_t)(k0 + r) * N + n0 + c]);
    __syncthreads();
    for (int r = r0; r < 32; r += 8) {
        int n = n0 + r;
        int np = n;
        float scale = 1.0f;
        if (permute) {
            int d = n / 36, rem = n - d * 36;
            int which = rem / 12, h = rem - which * 12;
            np = which * 768 + h * 64 + d;
            if (which == 0) scale = QSCALE;
        }
        float v = __bfloat162float(__hip_bfloat16_raw{(unsigned short)T[c][r]});
        Wt[(size_t)np * DIM + k0 + c] = (scale == 1.0f) ? T[c][r] : rne16(v * scale);
    }
}

// ---------------------------------------------------------------------------
// qkv = xb @ Wqkv (via permuted Wqt [2304][768]); glds-staged.
// R9: 128m x 256n tile, 512 thr / 8 waves (each 64x64 out), BK=64,
// R6's proven 2-barrier loop. Per-CU drain count HALVES (2.25 blocks/CU x
// 12 iters vs 4.5 x 12) while each drain covers 2x the output; A L2-traffic
// halves. LDS 48 KB single-buffered; launch_bounds(512,4) pins VGPR<=128 so
// 2 blocks/CU co-reside. 768 % 256 == 0 -> each tile wholly in Q, K, or V.
// Fragment-linear outputs for the 32x32x16 attention consumer (R4 notes).
// ---------------------------------------------------------------------------
__global__ __launch_bounds__(512, 4) void gemm_qkv(const short* __restrict__ A,
                                                   const short* __restrict__ Bt,
                                                   short* __restrict__ Qo,
                                                   short* __restrict__ Ko,
                                                   short* __restrict__ Vto) {
    __shared__ short As[128 * 64];   // 16 KB
    __shared__ short Bs[256 * 64];   // 32 KB
    const int tid = threadIdx.x;
    const int lane = tid & 63, wave = tid >> 6;   // 8 waves
    const int l15 = lane & 15, quad = lane >> 4;

    // XCD swizzle: 8 XCDs x 8 m x 9 n = 576 blocks
    const int flat = blockIdx.x;
    const int xcd = flat & 7;
    const int local = flat >> 3;                  // 0..71
    const int mloc = local & 7, nloc = local >> 3;
    const int m0 = (xcd * 8 + mloc) * 128;
    const int n0 = nloc * 256;

    const int wm = (wave >> 2) * 64;              // {0,64}
    const int wn = (wave & 3) * 64;               // {0,64,128,192}
    const int r8 = wave * 8 + (lane >> 3);        // 0..63
    const int c8 = lane & 7;
    const int sc = ((c8 ^ (r8 & 7)) << 3);        // swizzled source chunk (elems)

    const int sn = n0 + wn;                       // wave-uniform output chunk
    const int which = sn / 768;
    const bool swapAB = (which != 2);             // Q/K waves compute C^T

    floatx4 acc[4][4] = {};
    for (int k0 = 0; k0 < DIM; k0 += 64) {
#pragma unroll
        for (int i = 0; i < 2; ++i) {
            int row = i * 64 + r8;
            glds16(&A[(size_t)(m0 + row) * DIM + k0 + sc], &As[(size_t)(i * 64 + wave * 8) * 64]);
        }
#pragma unroll
        for (int i = 0; i < 4; ++i) {
            int row = i * 64 + r8;
            glds16(&Bt[(size_t)(n0 + row) * DIM + k0 + sc], &Bs[(size_t)(i * 64 + wave * 8) * 64]);
        }
        __syncthreads();
#pragma unroll
        for (int ks = 0; ks < 2; ++ks) {
            short8 a[4], b[4];
#pragma unroll
            for (int mt = 0; mt < 4; ++mt)
                a[mt] = *(const short8*)&As[swz8(wm + mt * 16 + l15, ks * 32 + quad * 8)];
#pragma unroll
            for (int nt = 0; nt < 4; ++nt)
                b[nt] = *(const short8*)&Bs[swz8(wn + nt * 16 + l15, ks * 32 + quad * 8)];
            if (swapAB) {
#pragma unroll
                for (int mt = 0; mt < 4; ++mt)
#pragma unroll
                    for (int nt = 0; nt < 4; ++nt)
                        acc[mt][nt] = mfma16(b[nt], a[mt], acc[mt][nt]);
            } else {
#pragma unroll
                for (int mt = 0; mt < 4; ++mt)
#pragma unroll
                    for (int nt = 0; nt < 4; ++nt)
                        acc[mt][nt] = mfma16(a[mt], b[nt], acc[mt][nt]);
            }
        }
        __syncthreads();
    }

    // ---- epilogue: direct stores into fragment-linear tiles ----
    const int h = (sn - which * 768) >> 6;
    const int bb = (m0 + wm) >> 11;

    if (which != 2) {
        // swapped acc: lane covers t = wm + mt*16 + l15, d = nt*16 + quad*4 .. +3
        const bool isQ = (which == 0);
        short* dst = isQ ? Qo : Ko;
        const size_t tb = isQ
            ? ((size_t)(bb * HEADS + h) * 16 + ((m0 & 2047) >> 7)) * 8192
            : ((size_t)(bb * HEADS + h) * 32 + (((m0 + wm) & 2047) >> 6)) * 4096;
#pragma unroll
        for (int mt = 0; mt < 4; ++mt)
#pragma unroll
            for (int nt = 0; nt < 4; ++nt) {
                int cl = (mt & 1) * 16 + l15 + 32 * (quad >> 1);
                int off = isQ
                    ? (((wm >> 5) + (mt >> 1)) * 2048 + nt * 512 + cl * 8 + (quad & 1) * 4)
                    : (((mt >> 1) * 4 + nt) * 512 + cl * 8 + (quad & 1) * 4);
                uint2 pk;
                pk.x = pack2(acc[mt][nt][0], acc[mt][nt][1]);
                pk.y = pack2(acc[mt][nt][2], acc[mt][nt][3]);
                *(uint2*)&dst[tb + off] = pk;
            }
    } else {
        // V (unswapped): lane covers d = nt*16 + l15, kv = wm-rel mt*16 + quad*4 + r
        const size_t tb = ((size_t)(bb * HEADS + h) * 32 + (((m0 + wm) & 2047) >> 6)) * 4096;
#pragma unroll
        for (int mt = 0; mt < 4; ++mt)
#pragma unroll
            for (int nt = 0; nt < 4; ++nt) {
                int cl = (nt & 1) * 16 + l15 + 32 * (quad >> 1);
                int off = ((nt >> 1) * 4 + mt) * 512 + cl * 8 + (quad & 1) * 4;
                uint2 pk;
                pk.x = pack2(acc[mt][nt][0], acc[mt][nt][1]);  // consecutive kv
                pk.y = pack2(acc[mt][nt][2], acc[mt][nt][3]);
                *(uint2*)&Vto[tb + off] = pk;
            }
    }
}

// ---------------------------------------------------------------------------
// MFMA flash attention, 32x32x16, fragment-linear tiles, FULLY INTERLEAVED
// (exact R6 best: ~64 us):
//   4 waves x 32 q-rows over the full 64-kv tile; QK(t)+PV(t-1) MFMAs
//   interleaved instruction-by-instruction; in-register P (permlane32_swap);
//   3-deep K/V LDS buffers, 1 barrier/iter, depth-1 prefetch.
// ---------------------------------------------------------------------------
__global__ __launch_bounds__(256, 3) void attn_mfma(const short* __restrict__ Q,
                                                    const short* __restrict__ K,
                                                    const short* __restrict__ Vt,
                                                    short* __restrict__ O) {
    // 3 buffers x (K 4096 | V 4096) shorts = 48 KB
    __shared__ __align__(16) short smem[24576];
    const int tid = threadIdx.x;
    const int lane = tid & 63, wave = tid >> 6;    // 4 waves
    const int l31 = lane & 31, hi = lane >> 5;
    const int flat = blockIdx.x;
    const int xcd = flat & 7, li = flat >> 3;      // li 0..95
    const int bh = xcd + (li % 6) * 8;             // bh % 8 == xcd (K/V L2-local)
    const int q0 = (li / 6) * 128;
    const size_t base = (size_t)bh * SEQ * DHEAD;  // shorts
    const int lane8 = lane * 8;

    // ---- stage Q tile (16 KB fragment-linear) into smem[0..8192) ----
    {
        size_t qtb = base + (size_t)(q0 >> 7) * 8192;
#pragma unroll
        for (int c = 0; c < 4; ++c) {
            int s = wave * 4 + c;
            glds16(&Q[qtb + s * 512 + lane8], &smem[s * 512]);
        }
    }
    __syncthreads();
    short8 qf[4];   // B-frags: q-col = l31 (wave's group), k = d = ks*16+hi*8+e
#pragma unroll
    for (int ks = 0; ks < 4; ++ks)
        qf[ks] = *(const short8*)&smem[wave * 2048 + ks * 512 + lane8];
    __syncthreads();   // Q in regs; smem free for K/V buffers

    floatx16 o0 = {}, o1 = {};   // O^T rows d = (reg&3)+8*(reg>>2)+4*hi (+32 for o1), col q = l31
    float lsum = 0.f;

    const int seg0 = (2 * wave + 0) * 512;   // this wave's staging segments
    const int seg1 = (2 * wave + 1) * 512;

#define STAGE(tt, buf) {                                                \
        size_t ktb_ = base + (size_t)(tt) * 4096;                       \
        glds16(&K[ktb_ + seg0 + lane8], &(buf)[seg0]);                  \
        glds16(&K[ktb_ + seg1 + lane8], &(buf)[seg1]);                  \
        glds16(&Vt[ktb_ + seg0 + lane8], &(buf)[4096 + seg0]);          \
        glds16(&Vt[ktb_ + seg1 + lane8], &(buf)[4096 + seg1]);          \
    }

    // p = exp2(s); pack + permlane32_swap -> PV B-frags (in-register).
    // D reg r (=rr+4*blk) holds kv = rr + 8*blk + 4*hi (within its 32-kv tile);
    // B-frag dword j needs kv = hi*8 + 2j per 16-kv chunk: P32-swap blk pairs.
#define SOFTPACK(SA, PFA, PFB) {                                              \
        float e0_  = __builtin_amdgcn_exp2f(SA[0]);                           \
        float e1_  = __builtin_amdgcn_exp2f(SA[1]);                           \
        float e2_  = __builtin_amdgcn_exp2f(SA[2]);                           \
        float e3_  = __builtin_amdgcn_exp2f(SA[3]);                           \
        float e4_  = __builtin_amdgcn_exp2f(SA[4]);                           \
        float e5_  = __builtin_amdgcn_exp2f(SA[5]);                           \
        float e6_  = __builtin_amdgcn_exp2f(SA[6]);                           \
        float e7_  = __builtin_amdgcn_exp2f(SA[7]);                           \
        float e8_  = __builtin_amdgcn_exp2f(SA[8]);                           \
        float e9_  = __builtin_amdgcn_exp2f(SA[9]);                           \
        float e10_ = __builtin_amdgcn_exp2f(SA[10]);                          \
        float e11_ = __builtin_amdgcn_exp2f(SA[11]);                          \
        float e12_ = __builtin_amdgcn_exp2f(SA[12]);                          \
        float e13_ = __builtin_amdgcn_exp2f(SA[13]);                          \
        float e14_ = __builtin_amdgcn_exp2f(SA[14]);                          \
        float e15_ = __builtin_amdgcn_exp2f(SA[15]);                          \
        lsum += (((e0_ + e1_) + (e2_ + e3_)) + ((e4_ + e5_) + (e6_ + e7_)))   \
              + (((e8_ + e9_) + (e10_ + e11_)) + ((e12_ + e13_) + (e14_ + e15_))); \
        unsigned A0_ = cvtpk(e0_, e1_),   A1_ = cvtpk(e2_, e3_);              \
        unsigned B0_ = cvtpk(e4_, e5_),   B1_ = cvtpk(e6_, e7_);              \
        unsigned C0_ = cvtpk(e8_, e9_),   C1_ = cvtpk(e10_, e11_);            \
        unsigned E0_ = cvtpk(e12_, e13_), E1_ = cvtpk(e14_, e15_);            \
        asm("v_permlane32_swap_b32 %0, %1" : "+v"(A0_), "+v"(B0_));           \
        asm("v_permlane32_swap_b32 %0, %1" : "+v"(A1_), "+v"(B1_));           \
        asm("v_permlane32_swap_b32 %0, %1" : "+v"(C0_), "+v"(E0_));           \
        asm("v_permlane32_swap_b32 %0, %1" : "+v"(C1_), "+v"(E1_));           \
        uintx4 wa_ = {A0_, A1_, B0_, B1_};                                    \
        uintx4 wb_ = {C0_, C1_, E0_, E1_};                                    \
        PFA = __builtin_bit_cast(short8, wa_);                                \
        PFB = __builtin_bit_cast(short8, wb_);                                \
    }

    short8 pfp[4];   // pf(t-1) carry

    // prologue: stage tile 0 -> buf0
    STAGE(0, smem);
    // ---- t = 0 peel: QK + softmax only (no PV yet) ----
    {
        __syncthreads();               // tile 0 resident
        STAGE(1, smem + 8192);         // prefetch tile 1 -> buf1
        floatx16 sa0 = {}, sa1 = {};
        __builtin_amdgcn_s_setprio(1);
#pragma unroll
        for (int c = 0; c < 4; ++c) {
            short8 kf0 = *(const short8*)&smem[c * 512 + lane8];
            short8 kf1 = *(const short8*)&smem[(4 + c) * 512 + lane8];
            sa0 = mfma32(kf0, qf[c], sa0);
            sa1 = mfma32(kf1, qf[c], sa1);
        }
        __builtin_amdgcn_s_setprio(0);
        SOFTPACK(sa0, pfp[0], pfp[1])
        SOFTPACK(sa1, pfp[2], pfp[3])
    }

    int bp = 0, bc = 1, bn = 2;
    for (int t = 1; t < 32; ++t) {
        __syncthreads();               // tile t resident; buf[bn] free
        const short* curb = smem + bc * 8192;        // K(t)
        const short* prvv = smem + bp * 8192 + 4096; // V(t-1)
        if (t < 31)
            STAGE(t + 1, smem + bn * 8192);

        // ---- fused QK(t) + PV(t-1): 4 chains round-robin, no MFMA stalls ----
        floatx16 sa0 = {}, sa1 = {};
        __builtin_amdgcn_s_setprio(1);
#pragma unroll
        for (int c = 0; c < 4; ++c) {
            short8 kf0 = *(const short8*)&curb[c * 512 + lane8];
            short8 kf1 = *(const short8*)&curb[(4 + c) * 512 + lane8];
            short8 vf0 = *(const short8*)&prvv[c * 512 + lane8];
            short8 vf1 = *(const short8*)&prvv[(4 + c) * 512 + lane8];
            sa0 = mfma32(kf0, qf[c], sa0);
            o0  = mfma32(vf0, pfp[c], o0);
            sa1 = mfma32(kf1, qf[c], sa1);
            o1  = mfma32(vf1, pfp[c], o1);
        }
        __builtin_amdgcn_s_setprio(0);

        // sm(t) overwrites pfp in place (PV(t-1) reads precede in prog order)
        SOFTPACK(sa0, pfp[0], pfp[1])
        SOFTPACK(sa1, pfp[2], pfp[3])

        // rotate buffers
        bp = bc; bc = bn; bn = (bn == 2) ? 0 : bn + 1;
    }
    // final PV for tile 31 (its buffer is bp after the last rotate)
    {
        const short* prvv = smem + bp * 8192 + 4096;
        __builtin_amdgcn_s_setprio(1);
#pragma unroll
        for (int c = 0; c < 4; ++c) {
            short8 vf0 = *(const short8*)&prvv[c * 512 + lane8];
            short8 vf1 = *(const short8*)&prvv[(4 + c) * 512 + lane8];
            o0 = mfma32(vf0, pfp[c], o0);
            o1 = mfma32(vf1, pfp[c], o1);
        }
        __builtin_amdgcn_s_setprio(0);
    }

#undef SOFTPACK
#undef STAGE

    // ---- epilogue: lane pair (hi^1) holds the other 32 kv -> one xor-32 ----
    float s = lsum + __shfl_xor(lsum, 32);
    float inv = 1.f / s;

    const int b = bh / HEADS, h = bh - b * HEADS;
    const int tq = q0 + wave * 32 + l31;
    size_t rowo = ((size_t)(b * SEQ + tq)) * DIM + h * DHEAD;
#pragma unroll
    for (int blk = 0; blk < 4; ++blk) {
        int d0 = 8 * blk + 4 * hi;
        uint2 p0, p1;
        p0.x = cvtpk(o0[4 * blk + 0] * inv, o0[4 * blk + 1] * inv);
        p0.y = cvtpk(o0[4 * blk + 2] * inv, o0[4 * blk + 3] * inv);
        *(uint2*)&O[rowo + d0] = p0;
        p1.x = cvtpk(o1[4 * blk + 0] * inv, o1[4 * blk + 1] * inv);
        p1.y = cvtpk(o1[4 * blk + 2] * inv, o1[4 * blk + 3] * inv);
        *(uint2*)&O[rowo + 32 + d0] = p1;
    }
}

// ---------------------------------------------------------------------------
// out = attnB @ Wout (via Wot [768][768]), fp32 output; glds-staged.
// 64x128 tile: grid 768 = 3.0 blocks/CU even. C^T swap -> dwordx4 stores.
// ---------------------------------------------------------------------------
__global__ __launch_bounds__(256) void gemm_out(const short* __restrict__ A,
                                                const short* __restrict__ Bt,
                                                float* __restrict__ out) {
    __shared__ short As[64 * 64];
    __shared__ short Bs[128 * 64];
    const int tid = threadIdx.x;
    const int lane = tid & 63, wave = tid >> 6;
    const int l15 = lane & 15, quad = lane >> 4;
    const int m0 = blockIdx.y * 64, n0 = blockIdx.x * 128;
    const int wn = wave * 32;                 // wave's 32-col slice; rows shared
    const int r8 = wave * 8 + (lane >> 3);
    const int sc = (((lane & 7) ^ (r8 & 7)) << 3);

    floatx4 acc[4][2] = {};
    for (int k0 = 0; k0 < DIM; k0 += 64) {
#pragma unroll
        for (int i = 0; i < 2; ++i) {
            int row = i * 32 + r8;
            glds16(&A[(size_t)(m0 + row) * DIM + k0 + sc], &As[(size_t)(i * 32 + wave * 8) * 64]);
        }
#pragma unroll
        for (int i = 0; i < 4; ++i) {
            int row = i * 32 + r8;
            glds16(&Bt[(size_t)(n0 + row) * DIM + k0 + sc], &Bs[(size_t)(i * 32 + wave * 8) * 64]);
        }
        __syncthreads();
#pragma unroll
        for (int ks = 0; ks < 2; ++ks) {
            short8 a[4], b[2];
#pragma unroll
            for (int mt = 0; mt < 4; ++mt)
                a[mt] = *(const short8*)&As[swz8(mt * 16 + l15, ks * 32 + quad * 8)];
#pragma unroll
            for (int nt = 0; nt < 2; ++nt)
                b[nt] = *(const short8*)&Bs[swz8(wn + nt * 16 + l15, ks * 32 + quad * 8)];
#pragma unroll
            for (int mt = 0; mt < 4; ++mt)
#pragma unroll
                for (int nt = 0; nt < 2; ++nt)
                    acc[mt][nt] = mfma16(b[nt], a[mt], acc[mt][nt]);  // C^T
        }
        __syncthreads();
    }

    // swapped: m = mt*16+l15, n = wn+nt*16+quad*4..+3 -> dwordx4 stores
#pragma unroll
    for (int mt = 0; mt < 4; ++mt)
#pragma unroll
        for (int nt = 0; nt < 2; ++nt) {
            int m = m0 + mt * 16 + l15;
            int n = n0 + wn + nt * 16 + quad * 4;
            *(floatx4*)&out[(size_t)m * DIM + n] = acc[mt][nt];
        }
}

// ---------------------------------------------------------------------------
extern "C" void kernel_launch(void* const* d_in, const int* in_sizes, int n_in,
                              void* d_out, int out_size, void* d_ws, size_t ws_size,
                              hipStream_t stream) {
    const float* x    = (const float*)d_in[0];  // [4,2048,768] fp32
    const float* Wqkv = (const float*)d_in[1];  // [768,2304]  fp32
    const float* Wout = (const float*)d_in[2];  // [768,768]   fp32
    float* out = (float*)d_out;                 // [4,2048,768] fp32

    const size_t NE = (size_t)NROW * DIM;       // 6291456
    short* xb  = (short*)d_ws;                  // x bf16; later reused as attnB
    short* Wqt = xb + NE;                       // [2304][768] (col-permuted, Q-rows pre-scaled)
    short* Wot = Wqt + (size_t)QKVN * DIM;      // [768][768]
    short* Qw  = Wot + (size_t)DIM * DIM;       // fragment-linear 128q tiles
    short* Kw  = Qw + NE;                       // fragment-linear 64kv tiles
    short* Vtw = Kw + NE;                       // fragment-linear V^T tiles

    prep<<<6144 + 1728 + 576, 256, 0, stream>>>(x, xb, Wqkv, Wqt, Wout, Wot);
    gemm_qkv<<<8 * 8 * 9, 512, 0, stream>>>(xb, Wqt, Qw, Kw, Vtw);
    // xb (x in bf16) is dead after gemm_qkv -> reuse as attention output buffer
    attn_mfma<<<768, 256, 0, stream>>>(Qw, Kw, Vtw, xb);
    gemm_out<<<dim3(DIM / 128, NROW / 64), 256, 0, stream>>>(xb, Wot, out);
}

// Round 10
// 206.986 us; speedup vs baseline: 2.2086x; 2.2086x over previous
//
#include <hip/hip_runtime.h>
#include <hip/hip_bf16.h>

#define DIM    768
#define HEADS  12
#define DHEAD  64
#define BATCH  4
#define SEQ    2048
#define NROW   (BATCH * SEQ)   // 8192
#define QKVN   (3 * DIM)       // 2304
#define FACTOR 0.125f          // 64^-0.5
#define QSCALE 0.18033688011112042f  // FACTOR * log2(e), folded into Wqt rows <768

typedef __attribute__((ext_vector_type(8))) short short8;    // 8 bf16 = 4 VGPR
typedef __attribute__((ext_vector_type(4))) float floatx4;   // 16x16 C/D
typedef __attribute__((ext_vector_type(16))) float floatx16; // 32x32 C/D
typedef __attribute__((ext_vector_type(4))) unsigned uintx4;

__device__ __forceinline__ floatx4 mfma16(short8 a, short8 b, floatx4 c) {
    return __builtin_amdgcn_mfma_f32_16x16x32_bf16(a, b, c, 0, 0, 0);
}
__device__ __forceinline__ floatx16 mfma32(short8 a, short8 b, floatx16 c) {
    return __builtin_amdgcn_mfma_f32_32x32x16_bf16(a, b, c, 0, 0, 0);
}

// async global->LDS, 16B per lane; lds base must be wave-uniform,
// deposits at base + lane*16 (lane-ordered source REQUIRED for coalescing)
__device__ __forceinline__ void glds16(const void* g, void* l) {
    __builtin_amdgcn_global_load_lds((const __attribute__((address_space(1))) void*)g,
                                     (__attribute__((address_space(3))) void*)l,
                                     16, 0, 0);
}

// branchless RNE fp32->bf16 (finite values only)
__device__ __forceinline__ short rne16(float f) {
    unsigned u = __builtin_bit_cast(unsigned, f);
    return (short)((u + 0x7fffu + ((u >> 16) & 1u)) >> 16);
}
__device__ __forceinline__ unsigned pack2(float lo, float hi) {
    unsigned ul = __builtin_bit_cast(unsigned, lo);
    unsigned uh = __builtin_bit_cast(unsigned, hi);
    ul = (ul + 0x7fffu + ((ul >> 16) & 1u)) >> 16;
    uh = (uh + 0x7fffu + ((uh >> 16) & 1u)) & 0xffff0000u;
    return ul | uh;
}
// HW packed RNE cvt (gfx950): lo -> bits[15:0], hi -> bits[31:16]
__device__ __forceinline__ unsigned cvtpk(float lo, float hi) {
    unsigned r;
    asm("v_cvt_pk_bf16_f32 %0, %1, %2" : "=v"(r) : "v"(lo), "v"(hi));
    return r;
}

// XOR-swizzled tile addressing (GEMM LDS staging paths)
__device__ __forceinline__ int swz8(int row, int col) {
    return (row << 6) + ((((col >> 3) ^ row) & 7) << 3) + (col & 7);
}

// ---------------------------------------------------------------------------
// prep (fused): blocks [0,6144)   : x fp32 -> bf16
//               blocks [6144,7872): Wqkv transpose+permute (+QSCALE rows<768)
//               blocks [7872,8448): Wout transpose
// ---------------------------------------------------------------------------
__global__ __launch_bounds__(256) void prep(const float* __restrict__ x,
                                            short* __restrict__ xb,
                                            const float* __restrict__ Wqkv,
                                            short* __restrict__ Wqt,
                                            const float* __restrict__ Wout,
                                            short* __restrict__ Wot) {
    __shared__ short T[32][33];
    int blk = blockIdx.x;
    if (blk < 6144) {
        int g = blk * 256 + threadIdx.x;
        float4 v = ((const float4*)x)[g];
        uint2 o;
        o.x = pack2(v.x, v.y);
        o.y = pack2(v.z, v.w);
        ((uint2*)xb)[g] = o;
        return;
    }
    blk -= 6144;
    const float* W;
    short* Wt;
    int N, permute, bx, by;
    if (blk < 1728) { W = Wqkv; Wt = Wqt; N = QKVN; permute = 1; bx = blk % 72; by = blk / 72; }
    else { blk -= 1728; W = Wout; Wt = Wot; N = DIM; permute = 0; bx = blk % 24; by = blk / 24; }

    int n0 = bx * 32, k0 = by * 32;
    int c = threadIdx.x & 31, r0 = threadIdx.x >> 5;
    for (int r = r0; r < 32; r += 8)
        T[r][c] = rne16(W[(size_t)(k0 + r) * N + n0 + c]);
    __syncthreads();
    for (int r = r0; r < 32; r += 8) {
        int n = n0 + r;
        int np = n;
        float scale = 1.0f;
        if (permute) {
            int d = n / 36, rem = n - d * 36;
            int which = rem / 12, h = rem - which * 12;
            np = which * 768 + h * 64 + d;
            if (which == 0) scale = QSCALE;
        }
        float v = __bfloat162float(__hip_bfloat16_raw{(unsigned short)T[c][r]});
        Wt[(size_t)np * DIM + k0 + c] = (scale == 1.0f) ? T[c][r] : rne16(v * scale);
    }
}

// ---------------------------------------------------------------------------
// qkv = xb @ Wqkv (via permuted Wqt [2304][768]); glds-staged.
// R6 proven version: 128x128 tile, 256 thr, BK=64, 2-barrier loop,
// 4.5 blocks/CU implicit overlap. Fragment-linear outputs (R4 notes).
// ---------------------------------------------------------------------------
__global__ __launch_bounds__(256) void gemm_qkv(const short* __restrict__ A,
                                                const short* __restrict__ Bt,
                                                short* __restrict__ Qo,
                                                short* __restrict__ Ko,
                                                short* __restrict__ Vto) {
    __shared__ short As[128 * 64];
    __shared__ short Bs[128 * 64];
    const int tid = threadIdx.x;
    const int lane = tid & 63, wave = tid >> 6;
    const int l15 = lane & 15, quad = lane >> 4;

    // XCD swizzle: 8 XCDs x 8 m x 18 n = 1152 blocks
    const int flat = blockIdx.x;
    const int xcd = flat & 7;
    const int local = flat >> 3;
    const int mloc = local & 7, nloc = local >> 3;
    const int m0 = (xcd * 8 + mloc) * 128;
    const int n0 = nloc * 128;

    const int wm = (wave >> 1) * 64, wn = (wave & 1) * 64;
    const int r8 = wave * 8 + (lane >> 3);
    const int c8 = lane & 7;
    const int sc = ((c8 ^ (r8 & 7)) << 3);   // swizzled source chunk (elems)

    const int sn = n0 + wn;                  // wave-uniform output chunk
    const int which = sn / 768;
    const bool swapAB = (which != 2);        // Q/K waves compute C^T

    floatx4 acc[4][4] = {};
    for (int k0 = 0; k0 < DIM; k0 += 64) {
#pragma unroll
        for (int i = 0; i < 4; ++i) {
            int row = i * 32 + r8;
            glds16(&A[(size_t)(m0 + row) * DIM + k0 + sc], &As[(size_t)(i * 32 + wave * 8) * 64]);
            glds16(&Bt[(size_t)(n0 + row) * DIM + k0 + sc], &Bs[(size_t)(i * 32 + wave * 8) * 64]);
        }
        __syncthreads();
#pragma unroll
        for (int ks = 0; ks < 2; ++ks) {
            short8 a[4], b[4];
#pragma unroll
            for (int mt = 0; mt < 4; ++mt)
                a[mt] = *(const short8*)&As[swz8(wm + mt * 16 + l15, ks * 32 + quad * 8)];
#pragma unroll
            for (int nt = 0; nt < 4; ++nt)
                b[nt] = *(const short8*)&Bs[swz8(wn + nt * 16 + l15, ks * 32 + quad * 8)];
            if (swapAB) {
#pragma unroll
                for (int mt = 0; mt < 4; ++mt)
#pragma unroll
                    for (int nt = 0; nt < 4; ++nt)
                        acc[mt][nt] = mfma16(b[nt], a[mt], acc[mt][nt]);
            } else {
#pragma unroll
                for (int mt = 0; mt < 4; ++mt)
#pragma unroll
                    for (int nt = 0; nt < 4; ++nt)
                        acc[mt][nt] = mfma16(a[mt], b[nt], acc[mt][nt]);
            }
        }
        __syncthreads();
    }

    // ---- epilogue: direct stores into fragment-linear tiles ----
    const int h = (sn - which * 768) >> 6;
    const int bb = (m0 + wm) >> 11;

    if (which != 2) {
        // swapped acc: lane covers t = wm + mt*16 + l15, d = nt*16 + quad*4 .. +3
        const bool isQ = (which == 0);
        short* dst = isQ ? Qo : Ko;
        const size_t tb = isQ
            ? ((size_t)(bb * HEADS + h) * 16 + ((m0 & 2047) >> 7)) * 8192
            : ((size_t)(bb * HEADS + h) * 32 + (((m0 + wm) & 2047) >> 6)) * 4096;
#pragma unroll
        for (int mt = 0; mt < 4; ++mt)
#pragma unroll
            for (int nt = 0; nt < 4; ++nt) {
                int cl = (mt & 1) * 16 + l15 + 32 * (quad >> 1);
                int off = isQ
                    ? (((wm >> 5) + (mt >> 1)) * 2048 + nt * 512 + cl * 8 + (quad & 1) * 4)
                    : (((mt >> 1) * 4 + nt) * 512 + cl * 8 + (quad & 1) * 4);
                uint2 pk;
                pk.x = pack2(acc[mt][nt][0], acc[mt][nt][1]);
                pk.y = pack2(acc[mt][nt][2], acc[mt][nt][3]);
                *(uint2*)&dst[tb + off] = pk;
            }
    } else {
        // V (unswapped): lane covers d = nt*16 + l15, kv = wm-rel mt*16 + quad*4 + r
        const size_t tb = ((size_t)(bb * HEADS + h) * 32 + (((m0 + wm) & 2047) >> 6)) * 4096;
#pragma unroll
        for (int mt = 0; mt < 4; ++mt)
#pragma unroll
            for (int nt = 0; nt < 4; ++nt) {
                int cl = (nt & 1) * 16 + l15 + 32 * (quad >> 1);
                int off = ((nt >> 1) * 4 + mt) * 512 + cl * 8 + (quad & 1) * 4;
                uint2 pk;
                pk.x = pack2(acc[mt][nt][0], acc[mt][nt][1]);  // consecutive kv
                pk.y = pack2(acc[mt][nt][2], acc[mt][nt][3]);
                *(uint2*)&Vto[tb + off] = pk;
            }
    }
}

// ---------------------------------------------------------------------------
// MFMA flash attention, 32x32x16, fragment-linear tiles, FULLY INTERLEAVED
// (R6 best: ~64 us):
//   4 waves x 32 q-rows over the full 64-kv tile; QK(t)+PV(t-1) MFMAs
//   interleaved instruction-by-instruction; in-register P (permlane32_swap);
//   3-deep K/V LDS buffers, 1 barrier/iter, depth-1 prefetch.
// ---------------------------------------------------------------------------
__global__ __launch_bounds__(256, 3) void attn_mfma(const short* __restrict__ Q,
                                                    const short* __restrict__ K,
                                                    const short* __restrict__ Vt,
                                                    short* __restrict__ O) {
    // 3 buffers x (K 4096 | V 4096) shorts = 48 KB
    __shared__ __align__(16) short smem[24576];
    const int tid = threadIdx.x;
    const int lane = tid & 63, wave = tid >> 6;    // 4 waves
    const int l31 = lane & 31, hi = lane >> 5;
    const int flat = blockIdx.x;
    const int xcd = flat & 7, li = flat >> 3;      // li 0..95
    const int bh = xcd + (li % 6) * 8;             // bh % 8 == xcd (K/V L2-local)
    const int q0 = (li / 6) * 128;
    const size_t base = (size_t)bh * SEQ * DHEAD;  // shorts
    const int lane8 = lane * 8;

    // ---- stage Q tile (16 KB fragment-linear) into smem[0..8192) ----
    {
        size_t qtb = base + (size_t)(q0 >> 7) * 8192;
#pragma unroll
        for (int c = 0; c < 4; ++c) {
            int s = wave * 4 + c;
            glds16(&Q[qtb + s * 512 + lane8], &smem[s * 512]);
        }
    }
    __syncthreads();
    short8 qf[4];   // B-frags: q-col = l31 (wave's group), k = d = ks*16+hi*8+e
#pragma unroll
    for (int ks = 0; ks < 4; ++ks)
        qf[ks] = *(const short8*)&smem[wave * 2048 + ks * 512 + lane8];
    __syncthreads();   // Q in regs; smem free for K/V buffers

    floatx16 o0 = {}, o1 = {};   // O^T rows d = (reg&3)+8*(reg>>2)+4*hi (+32 for o1), col q = l31
    float lsum = 0.f;

    const int seg0 = (2 * wave + 0) * 512;   // this wave's staging segments
    const int seg1 = (2 * wave + 1) * 512;

#define STAGE(tt, buf) {                                                \
        size_t ktb_ = base + (size_t)(tt) * 4096;                       \
        glds16(&K[ktb_ + seg0 + lane8], &(buf)[seg0]);                  \
        glds16(&K[ktb_ + seg1 + lane8], &(buf)[seg1]);                  \
        glds16(&Vt[ktb_ + seg0 + lane8], &(buf)[4096 + seg0]);          \
        glds16(&Vt[ktb_ + seg1 + lane8], &(buf)[4096 + seg1]);          \
    }

    // p = exp2(s); pack + permlane32_swap -> PV B-frags (in-register).
    // D reg r (=rr+4*blk) holds kv = rr + 8*blk + 4*hi (within its 32-kv tile);
    // B-frag dword j needs kv = hi*8 + 2j per 16-kv chunk: P32-swap blk pairs.
#define SOFTPACK(SA, PFA, PFB) {                                              \
        float e0_  = __builtin_amdgcn_exp2f(SA[0]);                           \
        float e1_  = __builtin_amdgcn_exp2f(SA[1]);                           \
        float e2_  = __builtin_amdgcn_exp2f(SA[2]);                           \
        float e3_  = __builtin_amdgcn_exp2f(SA[3]);                           \
        float e4_  = __builtin_amdgcn_exp2f(SA[4]);                           \
        float e5_  = __builtin_amdgcn_exp2f(SA[5]);                           \
        float e6_  = __builtin_amdgcn_exp2f(SA[6]);                           \
        float e7_  = __builtin_amdgcn_exp2f(SA[7]);                           \
        float e8_  = __builtin_amdgcn_exp2f(SA[8]);                           \
        float e9_  = __builtin_amdgcn_exp2f(SA[9]);                           \
        float e10_ = __builtin_amdgcn_exp2f(SA[10]);                          \
        float e11_ = __builtin_amdgcn_exp2f(SA[11]);                          \
        float e12_ = __builtin_amdgcn_exp2f(SA[12]);                          \
        float e13_ = __builtin_amdgcn_exp2f(SA[13]);                          \
        float e14_ = __builtin_amdgcn_exp2f(SA[14]);                          \
        float e15_ = __builtin_amdgcn_exp2f(SA[15]);                          \
        lsum += (((e0_ + e1_) + (e2_ + e3_)) + ((e4_ + e5_) + (e6_ + e7_)))   \
              + (((e8_ + e9_) + (e10_ + e11_)) + ((e12_ + e13_) + (e14_ + e15_))); \
        unsigned A0_ = cvtpk(e0_, e1_),   A1_ = cvtpk(e2_, e3_);              \
        unsigned B0_ = cvtpk(e4_, e5_),   B1_ = cvtpk(e6_, e7_);              \
        unsigned C0_ = cvtpk(e8_, e9_),   C1_ = cvtpk(e10_, e11_);            \
        unsigned E0_ = cvtpk(e12_, e13_), E1_ = cvtpk(e14_, e15_);            \
        asm("v_permlane32_swap_b32 %0, %1" : "+v"(A0_), "+v"(B0_));           \
        asm("v_permlane32_swap_b32 %0, %1" : "+v"(A1_), "+v"(B1_));           \
        asm("v_permlane32_swap_b32 %0, %1" : "+v"(C0_), "+v"(E0_));           \
        asm("v_permlane32_swap_b32 %0, %1" : "+v"(C1_), "+v"(E1_));           \
        uintx4 wa_ = {A0_, A1_, B0_, B1_};                                    \
        uintx4 wb_ = {C0_, C1_, E0_, E1_};                                    \
        PFA = __builtin_bit_cast(short8, wa_);                                \
        PFB = __builtin_bit_cast(short8, wb_);                                \
    }

    short8 pfp[4];   // pf(t-1) carry

    // prologue: stage tile 0 -> buf0
    STAGE(0, smem);
    // ---- t = 0 peel: QK + softmax only (no PV yet) ----
    {
        __syncthreads();               // tile 0 resident
        STAGE(1, smem + 8192);         // prefetch tile 1 -> buf1
        floatx16 sa0 = {}, sa1 = {};
        __builtin_amdgcn_s_setprio(1);
#pragma unroll
        for (int c = 0; c < 4; ++c) {
            short8 kf0 = *(const short8*)&smem[c * 512 + lane8];
            short8 kf1 = *(const short8*)&smem[(4 + c) * 512 + lane8];
            sa0 = mfma32(kf0, qf[c], sa0);
            sa1 = mfma32(kf1, qf[c], sa1);
        }
        __builtin_amdgcn_s_setprio(0);
        SOFTPACK(sa0, pfp[0], pfp[1])
        SOFTPACK(sa1, pfp[2], pfp[3])
    }

    int bp = 0, bc = 1, bn = 2;
    for (int t = 1; t < 32; ++t) {
        __syncthreads();               // tile t resident; buf[bn] free
        const short* curb = smem + bc * 8192;        // K(t)
        const short* prvv = smem + bp * 8192 + 4096; // V(t-1)
        if (t < 31)
            STAGE(t + 1, smem + bn * 8192);

        // ---- fused QK(t) + PV(t-1): 4 chains round-robin, no MFMA stalls ----
        floatx16 sa0 = {}, sa1 = {};
        __builtin_amdgcn_s_setprio(1);
#pragma unroll
        for (int c = 0; c < 4; ++c) {
            short8 kf0 = *(const short8*)&curb[c * 512 + lane8];
            short8 kf1 = *(const short8*)&curb[(4 + c) * 512 + lane8];
            short8 vf0 = *(const short8*)&prvv[c * 512 + lane8];
            short8 vf1 = *(const short8*)&prvv[(4 + c) * 512 + lane8];
            sa0 = mfma32(kf0, qf[c], sa0);
            o0  = mfma32(vf0, pfp[c], o0);
            sa1 = mfma32(kf1, qf[c], sa1);
            o1  = mfma32(vf1, pfp[c], o1);
        }
        __builtin_amdgcn_s_setprio(0);

        // sm(t) overwrites pfp in place (PV(t-1) reads precede in prog order)
        SOFTPACK(sa0, pfp[0], pfp[1])
        SOFTPACK(sa1, pfp[2], pfp[3])

        // rotate buffers
        bp = bc; bc = bn; bn = (bn == 2) ? 0 : bn + 1;
    }
    // final PV for tile 31 (its buffer is bp after the last rotate)
    {
        const short* prvv = smem + bp * 8192 + 4096;
        __builtin_amdgcn_s_setprio(1);
#pragma unroll
        for (int c = 0; c < 4; ++c) {
            short8 vf0 = *(const short8*)&prvv[c * 512 + lane8];
            short8 vf1 = *(const short8*)&prvv[(4 + c) * 512 + lane8];
            o0 = mfma32(vf0, pfp[c], o0);
            o1 = mfma32(vf1, pfp[c], o1);
        }
        __builtin_amdgcn_s_setprio(0);
    }

#undef SOFTPACK
#undef STAGE

    // ---- epilogue: lane pair (hi^1) holds the other 32 kv -> one xor-32 ----
    float s = lsum + __shfl_xor(lsum, 32);
    float inv = 1.f / s;

    const int b = bh / HEADS, h = bh - b * HEADS;
    const int tq = q0 + wave * 32 + l31;
    size_t rowo = ((size_t)(b * SEQ + tq)) * DIM + h * DHEAD;
#pragma unroll
    for (int blk = 0; blk < 4; ++blk) {
        int d0 = 8 * blk + 4 * hi;
        uint2 p0, p1;
        p0.x = cvtpk(o0[4 * blk + 0] * inv, o0[4 * blk + 1] * inv);
        p0.y = cvtpk(o0[4 * blk + 2] * inv, o0[4 * blk + 3] * inv);
        *(uint2*)&O[rowo + d0] = p0;
        p1.x = cvtpk(o1[4 * blk + 0] * inv, o1[4 * blk + 1] * inv);
        p1.y = cvtpk(o1[4 * blk + 2] * inv, o1[4 * blk + 3] * inv);
        *(uint2*)&O[rowo + 32 + d0] = p1;
    }
}

// ---------------------------------------------------------------------------
// out = attnB @ Wout (via Wot [768][768]), fp32 output; glds-staged.
// 64x128 tile: grid 768 = 3.0 blocks/CU even. C^T swap -> dwordx4 stores.
// ---------------------------------------------------------------------------
__global__ __launch_bounds__(256) void gemm_out(const short* __restrict__ A,
                                                const short* __restrict__ Bt,
                                                float* __restrict__ out) {
    __shared__ short As[64 * 64];
    __shared__ short Bs[128 * 64];
    const int tid = threadIdx.x;
    const int lane = tid & 63, wave = tid >> 6;
    const int l15 = lane & 15, quad = lane >> 4;
    const int m0 = blockIdx.y * 64, n0 = blockIdx.x * 128;
    const int wn = wave * 32;                 // wave's 32-col slice; rows shared
    const int r8 = wave * 8 + (lane >> 3);
    const int sc = (((lane & 7) ^ (r8 & 7)) << 3);

    floatx4 acc[4][2] = {};
    for (int k0 = 0; k0 < DIM; k0 += 64) {
#pragma unroll
        for (int i = 0; i < 2; ++i) {
            int row = i * 32 + r8;
            glds16(&A[(size_t)(m0 + row) * DIM + k0 + sc], &As[(size_t)(i * 32 + wave * 8) * 64]);
        }
#pragma unroll
        for (int i = 0; i < 4; ++i) {
            int row = i * 32 + r8;
            glds16(&Bt[(size_t)(n0 + row) * DIM + k0 + sc], &Bs[(size_t)(i * 32 + wave * 8) * 64]);
        }
        __syncthreads();
#pragma unroll
        for (int ks = 0; ks < 2; ++ks) {
            short8 a[4], b[2];
#pragma unroll
            for (int mt = 0; mt < 4; ++mt)
                a[mt] = *(const short8*)&As[swz8(mt * 16 + l15, ks * 32 + quad * 8)];
#pragma unroll
            for (int nt = 0; nt < 2; ++nt)
                b[nt] = *(const short8*)&Bs[swz8(wn + nt * 16 + l15, ks * 32 + quad * 8)];
#pragma unroll
            for (int mt = 0; mt < 4; ++mt)
#pragma unroll
                for (int nt = 0; nt < 2; ++nt)
                    acc[mt][nt] = mfma16(b[nt], a[mt], acc[mt][nt]);  // C^T
        }
        __syncthreads();
    }

    // swapped: m = mt*16+l15, n = wn+nt*16+quad*4..+3 -> dwordx4 stores
#pragma unroll
    for (int mt = 0; mt < 4; ++mt)
#pragma unroll
        for (int nt = 0; nt < 2; ++nt) {
            int m = m0 + mt * 16 + l15;
            int n = n0 + wn + nt * 16 + quad * 4;
            *(floatx4*)&out[(size_t)m * DIM + n] = acc[mt][nt];
        }
}

// ---------------------------------------------------------------------------
extern "C" void kernel_launch(void* const* d_in, const int* in_sizes, int n_in,
                              void* d_out, int out_size, void* d_ws, size_t ws_size,
                              hipStream_t stream) {
    const float* x    = (const float*)d_in[0];  // [4,2048,768] fp32
    const float* Wqkv = (const float*)d_in[1];  // [768,2304]  fp32
    const float* Wout = (const float*)d_in[2];  // [768,768]   fp32
    float* out = (float*)d_out;                 // [4,2048,768] fp32

    const size_t NE = (size_t)NROW * DIM;       // 6291456
    short* xb  = (short*)d_ws;                  // x bf16; later reused as attnB
    short* Wqt = xb + NE;                       // [2304][768] (col-permuted, Q-rows pre-scaled)
    short* Wot = Wqt + (size_t)QKVN * DIM;      // [768][768]
    short* Qw  = Wot + (size_t)DIM * DIM;       // fragment-linear 128q tiles
    short* Kw  = Qw + NE;                       // fragment-linear 64kv tiles
    short* Vtw = Kw + NE;                       // fragment-linear V^T tiles

    prep<<<6144 + 1728 + 576, 256, 0, stream>>>(x, xb, Wqkv, Wqt, Wout, Wot);
    gemm_qkv<<<8 * 8 * 18, 256, 0, stream>>>(xb, Wqt, Qw, Kw, Vtw);
    // xb (x in bf16) is dead after gemm_qkv -> reuse as attention output buffer
    attn_mfma<<<768, 256, 0, stream>>>(Qw, Kw, Vtw, xb);
    gemm_out<<<dim3(DIM / 128, NROW / 64), 256, 0, stream>>>(xb, Wot, out);
}